// Round 3
// baseline (387.664 us; speedup 1.0000x reference)
//
#include <hip/hip_runtime.h>
#include <math.h>

#define N_CODES       1024
#define CODE_DIM      64
#define ROWS_PER_BLK  256
#define THREADS       256

// numpy pairwise_sum of fl32(a[c]^2), n=64, scalar-8 path — bit-exact vs ref.
__device__ __forceinline__ float np_sumsq64(const float* a) {
#pragma clang fp contract(off)
    float r[8];
    #pragma unroll
    for (int j = 0; j < 8; ++j) r[j] = a[j] * a[j];
    #pragma unroll
    for (int t = 1; t < 8; ++t) {
        #pragma unroll
        for (int j = 0; j < 8; ++j) {
            float p = a[t * 8 + j] * a[t * 8 + j];
            r[j] = r[j] + p;
        }
    }
    return ((r[0] + r[1]) + (r[2] + r[3])) + ((r[4] + r[5]) + (r[6] + r[7]));
}

__global__ __launch_bounds__(THREADS, 2) void vq_np_emul_kernel(
    const float* __restrict__ vec,   // [32][64][64][64]  (b, c, h, w)
    const float* __restrict__ cb,    // [1024][64]
    float* __restrict__ out)         // [32][64][64][64]  (b, h, w, c)
{
    __shared__ float Cs[N_CODES];
    __shared__ int   idxs[ROWS_PER_BLK];

    const int tid  = threadIdx.x;
    const int base = blockIdx.x * ROWS_PER_BLK;
    const int b    = base >> 12;
    const int hw0  = base & 4095;

    // ---- ||w_k||^2, numpy tree ----
    #pragma unroll
    for (int j = 0; j < N_CODES / THREADS; ++j) {
        const int k = tid + j * THREADS;
        Cs[k] = np_sumsq64(cb + k * CODE_DIM);
    }

    // ---- load row, then PIN it in VGPRs (defeats load-sinking / remat) ----
    float xr[CODE_DIM];
    const float* xin = vec + (size_t)b * 262144 + hw0 + tid;
    #pragma unroll
    for (int c = 0; c < CODE_DIM; ++c) xr[c] = xin[(size_t)c * 4096];
    #pragma unroll
    for (int c = 0; c < CODE_DIM; ++c) asm volatile("" : "+v"(xr[c]));

    const float S = np_sumsq64(xr);

    __syncthreads();

    // ---- k-loop, 4 independent serial FMA chains (ILP covers dep latency) ----
    float m  = INFINITY;
    int   mi = 0;
    for (int k0 = 0; k0 < N_CODES; k0 += 4) {
        const float* w0 = cb + (size_t)k0 * CODE_DIM;   // wave-uniform -> s_load
        const float* w1 = w0 + CODE_DIM;
        const float* w2 = w1 + CODE_DIM;
        const float* w3 = w2 + CODE_DIM;
        float d0 = 0.f, d1 = 0.f, d2 = 0.f, d3 = 0.f;
        #pragma unroll
        for (int c = 0; c < CODE_DIM; ++c) {
            d0 = __builtin_fmaf(xr[c], w0[c], d0);
            d1 = __builtin_fmaf(xr[c], w1[c], d1);
            d2 = __builtin_fmaf(xr[c], w2[c], d2);
            d3 = __builtin_fmaf(xr[c], w3[c], d3);
        }
        const float4 cv = *(const float4*)&Cs[k0];       // broadcast ds_read_b128
        const float t0 = __builtin_fmaf(-2.f, d0, S) + cv.x;  // == fl(S-2G)+C exactly
        const float t1 = __builtin_fmaf(-2.f, d1, S) + cv.y;
        const float t2 = __builtin_fmaf(-2.f, d2, S) + cv.z;
        const float t3 = __builtin_fmaf(-2.f, d3, S) + cv.w;
        if (t0 < m) { m = t0; mi = k0;     }   // strict <, ascending k:
        if (t1 < m) { m = t1; mi = k0 + 1; }   // numpy first-index argmin
        if (t2 < m) { m = t2; mi = k0 + 2; }
        if (t3 < m) { m = t3; mi = k0 + 3; }
    }

    idxs[tid] = mi;
    __syncthreads();

    // ---- cooperative gather + coalesced float4 output write ----
    const int c4 = (tid & 15) << 2;
    const int r0 = tid >> 4;
    for (int r = r0; r < ROWS_PER_BLK; r += 16) {
        const int w = idxs[r];
        const float4 v = *(const float4*)(cb + (size_t)w * CODE_DIM + c4);
        *(float4*)(out + (size_t)(base + r) * CODE_DIM + c4) = v;
    }
}

extern "C" void kernel_launch(void* const* d_in, const int* in_sizes, int n_in,
                              void* d_out, int out_size, void* d_ws, size_t ws_size,
                              hipStream_t stream) {
    const float* vec = (const float*)d_in[0];
    const float* cb  = (const float*)d_in[1];
    float* out = (float*)d_out;

    const int n_rows = 32 * 64 * 64;            // 131072
    dim3 grid(n_rows / ROWS_PER_BLK);           // 512
    dim3 block(THREADS);
    vq_np_emul_kernel<<<grid, block, 0, stream>>>(vec, cb, out);
}

// Round 4
// 316.333 us; speedup vs baseline: 1.2255x; 1.2255x over previous
//
#include <hip/hip_runtime.h>
#include <math.h>

#define N_CODES   1024
#define CODE_DIM  64
#define THREADS   256
#define KTILE     128
#define NTILES    (N_CODES / KTILE)   // 8

// numpy pairwise_sum of fl32(a[c]^2), n=64, scalar-8 tree — bit-exact vs ref.
__device__ __forceinline__ float np_sumsq64(const float* a) {
#pragma clang fp contract(off)
    float r[8];
    #pragma unroll
    for (int j = 0; j < 8; ++j) r[j] = a[j] * a[j];
    #pragma unroll
    for (int t = 1; t < 8; ++t) {
        #pragma unroll
        for (int j = 0; j < 8; ++j) {
            float p = a[t * 8 + j] * a[t * 8 + j];
            r[j] = r[j] + p;
        }
    }
    return ((r[0] + r[1]) + (r[2] + r[3])) + ((r[4] + r[5]) + (r[6] + r[7]));
}

__global__ __launch_bounds__(THREADS, 2) void vq_lds_kernel(
    const float* __restrict__ vec,   // [32][64][64][64]  (b, c, h, w)
    const float* __restrict__ cb,    // [1024][64]
    float* __restrict__ out)         // [32][64][64][64]  (b, h, w, c)
{
    __shared__ __align__(16) float sw[2][KTILE * CODE_DIM];  // 2 x 32 KB
    __shared__ __align__(16) float Cs[N_CODES];              // 4 KB
    __shared__ int idxs[THREADS];                            // 1 KB

    const int tid  = threadIdx.x;
    const int base = blockIdx.x * THREADS;
    const int b    = base >> 12;          // 4096 rows per batch image
    const int hw0  = base & 4095;

    // ---- ||w_k||^2, numpy tree (tiny, once, L2-hot) ----
    #pragma unroll
    for (int j = 0; j < N_CODES / THREADS; ++j) {
        const int k = tid + j * THREADS;
        Cs[k] = np_sumsq64(cb + k * CODE_DIM);
    }

    // ---- row into VGPRs (coalesced stride-4096 dword loads), then pin ----
    float xr[CODE_DIM];
    const float* xin = vec + (size_t)b * 262144 + hw0 + tid;
    #pragma unroll
    for (int c = 0; c < CODE_DIM; ++c) xr[c] = xin[(size_t)c * 4096];
    #pragma unroll
    for (int c = 0; c < CODE_DIM; ++c) asm volatile("" : "+v"(xr[c]));

    const float S = np_sumsq64(xr);

    // ---- stage codebook tile 0 into LDS (coalesced float4) ----
    const float4* cb4 = (const float4*)cb;
    #pragma unroll
    for (int j = 0; j < 8; ++j)
        ((float4*)sw[0])[j * THREADS + tid] = cb4[j * THREADS + tid];
    __syncthreads();

    float m  = INFINITY;
    int   mi = 0;

    for (int t = 0; t < NTILES; ++t) {
        const int cur = t & 1;

        // T14 async-split: issue next tile's global loads before compute
        float4 g[8];
        if (t + 1 < NTILES) {
            #pragma unroll
            for (int j = 0; j < 8; ++j)
                g[j] = cb4[(size_t)(t + 1) * (KTILE * CODE_DIM / 4) + j * THREADS + tid];
        }

        // ---- compute on current tile: 4 independent serial FMA chains ----
        const float* wbase = sw[cur];
        for (int k0 = 0; k0 < KTILE; k0 += 4) {
            const float* w0 = wbase + (size_t)(k0 + 0) * CODE_DIM;
            const float* w1 = wbase + (size_t)(k0 + 1) * CODE_DIM;
            const float* w2 = wbase + (size_t)(k0 + 2) * CODE_DIM;
            const float* w3 = wbase + (size_t)(k0 + 3) * CODE_DIM;
            float d0 = 0.f, d1 = 0.f, d2 = 0.f, d3 = 0.f;
            #pragma unroll
            for (int c4 = 0; c4 < 16; ++c4) {
                const float4 a0 = *(const float4*)(w0 + c4 * 4);  // broadcast ds_read_b128
                const float4 a1 = *(const float4*)(w1 + c4 * 4);
                const float4 a2 = *(const float4*)(w2 + c4 * 4);
                const float4 a3 = *(const float4*)(w3 + c4 * 4);
                // each chain: ascending c, serial FMA — bit-exact sgemm accumulator
                d0 = __builtin_fmaf(xr[c4*4+0], a0.x, d0);
                d0 = __builtin_fmaf(xr[c4*4+1], a0.y, d0);
                d0 = __builtin_fmaf(xr[c4*4+2], a0.z, d0);
                d0 = __builtin_fmaf(xr[c4*4+3], a0.w, d0);
                d1 = __builtin_fmaf(xr[c4*4+0], a1.x, d1);
                d1 = __builtin_fmaf(xr[c4*4+1], a1.y, d1);
                d1 = __builtin_fmaf(xr[c4*4+2], a1.z, d1);
                d1 = __builtin_fmaf(xr[c4*4+3], a1.w, d1);
                d2 = __builtin_fmaf(xr[c4*4+0], a2.x, d2);
                d2 = __builtin_fmaf(xr[c4*4+1], a2.y, d2);
                d2 = __builtin_fmaf(xr[c4*4+2], a2.z, d2);
                d2 = __builtin_fmaf(xr[c4*4+3], a2.w, d2);
                d3 = __builtin_fmaf(xr[c4*4+0], a3.x, d3);
                d3 = __builtin_fmaf(xr[c4*4+1], a3.y, d3);
                d3 = __builtin_fmaf(xr[c4*4+2], a3.z, d3);
                d3 = __builtin_fmaf(xr[c4*4+3], a3.w, d3);
            }
            const int kg = t * KTILE + k0;
            const float4 cv = *(const float4*)&Cs[kg];
            const float t0 = __builtin_fmaf(-2.f, d0, S) + cv.x;  // fl(S-2G)+C exactly
            const float t1 = __builtin_fmaf(-2.f, d1, S) + cv.y;
            const float t2 = __builtin_fmaf(-2.f, d2, S) + cv.z;
            const float t3 = __builtin_fmaf(-2.f, d3, S) + cv.w;
            if (t0 < m) { m = t0; mi = kg;     }   // strict <, ascending k:
            if (t1 < m) { m = t1; mi = kg + 1; }   // numpy first-index argmin
            if (t2 < m) { m = t2; mi = kg + 2; }
            if (t3 < m) { m = t3; mi = kg + 3; }
        }

        // write staged regs to the other buffer, then one barrier per tile
        if (t + 1 < NTILES) {
            #pragma unroll
            for (int j = 0; j < 8; ++j)
                ((float4*)sw[cur ^ 1])[j * THREADS + tid] = g[j];
        }
        __syncthreads();
    }

    idxs[tid] = mi;
    __syncthreads();

    // ---- cooperative gather + coalesced float4 output write ----
    const int c4 = (tid & 15) << 2;
    const int r0 = tid >> 4;
    for (int r = r0; r < THREADS; r += 16) {
        const int w = idxs[r];
        const float4 v = *(const float4*)(cb + (size_t)w * CODE_DIM + c4);
        *(float4*)(out + (size_t)(base + r) * CODE_DIM + c4) = v;
    }
}

extern "C" void kernel_launch(void* const* d_in, const int* in_sizes, int n_in,
                              void* d_out, int out_size, void* d_ws, size_t ws_size,
                              hipStream_t stream) {
    const float* vec = (const float*)d_in[0];
    const float* cb  = (const float*)d_in[1];
    float* out = (float*)d_out;

    const int n_rows = 32 * 64 * 64;            // 131072
    dim3 grid(n_rows / THREADS);                // 512
    dim3 block(THREADS);
    vq_lds_kernel<<<grid, block, 0, stream>>>(vec, cb, out);
}